// Round 10
// baseline (393.458 us; speedup 1.0000x reference)
//
#include <hip/hip_runtime.h>
#include <hip/hip_bf16.h>
#include <stdint.h>

// B=512, N=256, D=128, 4 layers. One block (512 thr, 8 waves) per batch.
// ALGORITHM (associativity): R = Attn*key/n = Z * (Qf * G * Pf^T) / n where
//   G = Z^T A Z = sum_{m<256} z_m z_m^T   (129x129 symmetric)
// Gbar = G[0:128,0:128], g = G[0:128,128]:
//   T1 = Gbar*P^T; M0 = Q*T1; m1 = Q*g;  R[:,c<128] = Zc*M0/n; R[:,128] = Zc*m1/n.
// STATE: master Z = bf16-hi in LDS (ZT, transposed [d][tok], XOR-SWIZZLED) +
// bf16-lo residual in regs (own rows). acc -> GLOBAL scratch (bf16-packed
// uint4, coalesced slot*512+tid) in the first 64 KB of this block's own d_out
// slice (layer 0 never reads it; output epilogue overwrites it).
// R10 changes vs R9 (which was latency/LDS-conflict bound: MfmaUtil 6.5%,
// VALUBusy 19%, SQ_LDS_BANK_CONFLICT 2.96e7 ~ 15-18% of cycles):
//  1) ZT XOR swizzle: elem (d,tok) @ d*256 + 8*((tok>>3)^(d&7)^((d>>3)&3))
//     + (tok&7). Any 16B-aligned pitch makes the D-main row-gather (fixed tok,
//     rows 8 apart) hit ONE bank set 8-way; the swizzle spreads it ~2-way.
//  2) tok-256 column removed from ZT; its readers use f32 z256f (broadcast).
//  3) Ping-pong Gb (G->GbA, Mc->GbB): one less barrier (4/layer).
//  4) acc uint4 prefetch at ti-loop top: global latency hidden under MFMAs.

using short8 = __attribute__((ext_vector_type(8))) short;
using f32x4  = __attribute__((ext_vector_type(4))) float;

#define MFMA16(A,B,C) __builtin_amdgcn_mfma_f32_16x16x32_bf16((A),(B),(C),0,0,0)

static __device__ __forceinline__ uint16_t f2bf(float f){
  union{__hip_bfloat16 h;uint16_t u;}c; c.h=__float2bfloat16(f); return c.u; }
static __device__ __forceinline__ uint32_t pk2(float lo,float hi){
  return (uint32_t)f2bf(lo) | ((uint32_t)f2bf(hi)<<16); }
static __device__ __forceinline__ float bfu(uint16_t u){ return __uint_as_float(((uint32_t)u)<<16); }
static __device__ __forceinline__ float bflo(uint32_t p){ return __uint_as_float(p<<16); }
static __device__ __forceinline__ float bfhi(uint32_t p){ return __uint_as_float(p&0xffff0000u); }

union F4 { uint32_t u[4]; short8 s8; };

// swizzled ZT index (u16 units), tok in [0,256)
static __device__ __forceinline__ int ztix(int d, int tok) {
  return (d << 8) + ((((tok >> 3) ^ (d & 7) ^ ((d >> 3) & 3)) & 31) << 3) + (tok & 7);
}

// ---- LDS geometry ----
#define BUFP  136                           // GbA/GbB pitch (u16)
#define SCRP  40                            // per-wave scratch pitch (u16)
#define ZT_OFF   0                          // 128*256*2 = 65,536
#define GBA_OFF  65536                      // 128*136*2 = 34,816
#define GBB_OFF  100352                     // 128*136*2 = 34,816
#define SCR_OFF  135168                     // 8*16*40*2 = 10,240
#define ZBAR_OFF 145408                     // 260*4 = 1,040
#define Z256_OFF 146448                     // 128*4 = 512
#define A128_OFF 146960                     // 256*4 = 1,024
#define A256_OFF 147984                     // 132*4 = 528
#define G_OFF    148512                     // 128*4 = 512
#define M1_OFF   149024                     // 128*4 = 512
#define LDS_TOTAL 149536

__global__ __launch_bounds__(512)
__attribute__((amdgpu_waves_per_eu(2, 2)))
void tf_layers(const float* __restrict__ Zin, const float* __restrict__ gamma,
               const uint16_t* __restrict__ Qg, const uint16_t* __restrict__ Pg,
               float* __restrict__ Zout)
{
  extern __shared__ char lds[];
  uint16_t* ZT    = (uint16_t*)(lds + ZT_OFF);   // [128][256] swizzled, tok<256
  uint16_t* GbA   = (uint16_t*)(lds + GBA_OFF);  // [128][BUFP]: Gbar
  uint16_t* GbB   = (uint16_t*)(lds + GBB_OFF);  // [128][BUFP]: Mc[c][d]
  float*    zbar  = (float*)(lds + ZBAR_OFF);    // [257] f32 master col 128
  float*    z256f = (float*)(lds + Z256_OFF);    // [128] f32 master row 256
  float*    acc128= (float*)(lds + A128_OFF);    // [256] f32 acc col 128
  float*    acc256= (float*)(lds + A256_OFF);    // [129] f32 acc row 256
  float*    gv    = (float*)(lds + G_OFF);       // [128] g = Gbar[:,128]
  float*    m1v   = (float*)(lds + M1_OFF);      // [128] m1 = Q*g

  const int tid = threadIdx.x, lane = tid & 63, w = tid >> 6;
  const int l15 = lane & 15, g4 = lane >> 4;
  const int b = blockIdx.x;
  const float inv_n = 1.0f/256.0f;

  uint16_t* scr = (uint16_t*)(lds + SCR_OFF) + w * 16 * SCRP;

  const float* Zb = Zin + (size_t)b*33153;   // 257*129
  float*       Zo = Zout + (size_t)b*33153;

  // acc scratch: 16B-aligned, inside this block's own output slice (64 KB).
  uint4* accb = (uint4*)(((uintptr_t)Zo + 15) & ~(uintptr_t)15);

  // ---- init: ZT (swizzled bf16 hi), zbar, z256f, acc arrays ----
  for (int i2 = tid; i2 < 33153; i2 += 512) {
    int r = i2/129, c = i2 - r*129;
    float v = Zb[i2];
    if (c < 128) { if (r < 256) ZT[ztix(c, r)] = f2bf(v); else z256f[c] = v; }
    else zbar[r] = v;
  }
  if (tid < 256) acc128[tid] = 0.0f;
  if (tid < 129) acc256[tid] = 0.0f;

  // lo residual regs for own rows (D-frag layout: row mb+4g4+rr, col 16it+l15)
  uint32_t lopk[2][16];
#pragma unroll
  for (int ti = 0; ti < 2; ++ti) {
    const int mb = 16*w + 128*ti;
#pragma unroll
    for (int it = 0; it < 8; ++it) {
      const float* zp = Zb + (size_t)(mb + 4*g4)*129 + 16*it + l15;
      float v0 = zp[0], v1 = zp[129], v2 = zp[258], v3 = zp[387];
      lopk[ti][2*it]   = pk2(v0 - bfu(f2bf(v0)), v1 - bfu(f2bf(v1)));
      lopk[ti][2*it+1] = pk2(v2 - bfu(f2bf(v2)), v3 - bfu(f2bf(v3)));
    }
  }

#pragma unroll 1
  for (int l = 0; l < 4; ++l) {
    const uint16_t* Ql  = Qg + l*16384;
    const uint16_t* Pl  = Pg + l*16384;
    const float*    gml = gamma + l*33153;
    const bool last = (l == 3);

    __syncthreads();   // bar A: ZT/zbar/z256f stable

    // ===== G: Gbar[i][j] = sum_{m<256} Z[m][i]Z[m][j]; g[i] = sum Z[m][i]zbar[m]
    {
      f32x4 gacc[8];
#pragma unroll
      for (int jt = 0; jt < 8; ++jt) gacc[jt] = (f32x4){0,0,0,0};
#pragma unroll
      for (int mw = 0; mw < 8; ++mw) {
        short8 af = *(const short8*)(ZT + ztix(16*w + l15, 32*mw + 8*g4));
#pragma unroll
        for (int jt = 0; jt < 8; ++jt) {
          short8 bf = *(const short8*)(ZT + ztix(16*jt + l15, 32*mw + 8*g4));
          gacc[jt] = MFMA16(af, bf, gacc[jt]);
        }
      }
      // symmetric write: lane holds G[i=16w+4g4+rr][j=16jt+l15] -> GbA[j][i]
#pragma unroll
      for (int jt = 0; jt < 8; ++jt)
        *(uint2*)(GbA + (16*jt+l15)*BUFP + 16*w + 4*g4) =
            make_uint2(pk2(gacc[jt][0],gacc[jt][1]), pk2(gacc[jt][2],gacc[jt][3]));
      // g GEMV: i = tid>>2, 4 lanes x 64 tokens
      {
        const int i = tid >> 2, q = lane & 3;
        float s = 0;
#pragma unroll
        for (int j = 0; j < 16; ++j) {
          uint2 zv = *(const uint2*)(ZT + ztix(i, 64*q + 4*j));
          f32x4 z4 = *(const f32x4*)(zbar + 64*q + 4*j);
          s += bflo(zv.x)*z4[0] + bfhi(zv.x)*z4[1] + bflo(zv.y)*z4[2] + bfhi(zv.y)*z4[3];
        }
        s += __shfl_xor(s,1); s += __shfl_xor(s,2);
        if (q == 0) gv[i] = s;
      }
    }
    __syncthreads();   // bar B: Gbar, g ready

    // ===== T1 = Gbar*P^T -> regs (wave w: cols c=16w+l15); m1 = Q*g =====
    uint32_t t1t[16];
    {
      short8 bq[4];
#pragma unroll
      for (int k = 0; k < 4; ++k)
        bq[k] = *(const short8*)(Pl + (16*w+l15)*128 + 32*k + 8*g4);
#pragma unroll
      for (int it = 0; it < 8; ++it) {
        f32x4 d4 = {0,0,0,0};
#pragma unroll
        for (int k = 0; k < 4; ++k) {
          short8 ag = *(const short8*)(GbA + (16*it+l15)*BUFP + 32*k + 8*g4);
          d4 = MFMA16(ag, bq[k], d4);
        }
        t1t[2*it]   = pk2(d4[0], d4[1]);
        t1t[2*it+1] = pk2(d4[2], d4[3]);
      }
      // m1[d] = sum_e Q[d][e] g[e]
      {
        const int d = tid >> 2, q = lane & 3;
        float s = 0;
#pragma unroll
        for (int j = 0; j < 4; ++j) {
          short8 qv = *(const short8*)(Ql + d*128 + 32*q + 8*j);
          f32x4 g0 = *(const f32x4*)(gv + 32*q + 8*j);
          f32x4 g1 = *(const f32x4*)(gv + 32*q + 8*j + 4);
          s += bfu((uint16_t)qv[0])*g0[0] + bfu((uint16_t)qv[1])*g0[1]
             + bfu((uint16_t)qv[2])*g0[2] + bfu((uint16_t)qv[3])*g0[3]
             + bfu((uint16_t)qv[4])*g1[0] + bfu((uint16_t)qv[5])*g1[1]
             + bfu((uint16_t)qv[6])*g1[2] + bfu((uint16_t)qv[7])*g1[3];
        }
        s += __shfl_xor(s,1); s += __shfl_xor(s,2);
        if (q == 0) m1v[d] = s;
      }
    }
    // (no barrier: Mc writes GbB, whose last readers finished before bar A)

    // ===== Mc[c][d] = sum_e T1t[c][e] Q[d][e]  (wave w: rows c=16w+l15) =====
    {
      F4 bfr[4];
#pragma unroll
      for (int k2 = 0; k2 < 4; ++k2) {
        *(uint2*)(scr + l15*SCRP + 4*g4)      = make_uint2(t1t[4*k2],   t1t[4*k2+1]);
        *(uint2*)(scr + l15*SCRP + 16 + 4*g4) = make_uint2(t1t[4*k2+2], t1t[4*k2+3]);
        bfr[k2].s8 = *(const short8*)(scr + l15*SCRP + 8*g4);  // same-wave RAW
      }
#pragma unroll
      for (int dt = 0; dt < 8; ++dt) {
        f32x4 d4 = {0,0,0,0};
#pragma unroll
        for (int k2 = 0; k2 < 4; ++k2) {
          short8 aq = *(const short8*)(Ql + (16*dt+l15)*128 + 32*k2 + 8*g4);
          d4 = MFMA16(aq, bfr[k2].s8, d4);
        }
        *(uint2*)(GbB + (16*w+l15)*BUFP + 16*dt + 4*g4) =
            make_uint2(pk2(d4[0],d4[1]), pk2(d4[2],d4[3]));
      }
    }
    __syncthreads();   // bar D: Mc (GbB), m1 ready

    // ===== D-main: R = Z*Mc/n + fused update (own rows); r128; r256 =====
    float r256v = 0.0f, rcv = 0.0f;
#pragma unroll
    for (int ti = 0; ti < 2; ++ti) {
      const int mb = 16*w + 128*ti;
      // acc prefetch (global latency hides under aw build + MFMAs)
      uint4 pf0, pf1, pf2, pf3;
      if (l > 0) {
        pf0 = accb[((ti*4 + 0) << 9) + tid];
        pf1 = accb[((ti*4 + 1) << 9) + tid];
        pf2 = accb[((ti*4 + 2) << 9) + tid];
        pf3 = accb[((ti*4 + 3) << 9) + tid];
      } else {
        pf0 = pf1 = pf2 = pf3 = make_uint4(0,0,0,0);
      }
      F4 aw[4];
      float rp = 0;
#pragma unroll
      for (int q = 0; q < 4; ++q) {      // A-frags: Z own rows from ZT columns
        uint16_t ev[8];
#pragma unroll
        for (int j = 0; j < 8; ++j) ev[j] = ZT[ztix(32*q + 8*g4 + j, mb + l15)];
        aw[q].u[0] = (uint32_t)ev[0] | ((uint32_t)ev[1]<<16);
        aw[q].u[1] = (uint32_t)ev[2] | ((uint32_t)ev[3]<<16);
        aw[q].u[2] = (uint32_t)ev[4] | ((uint32_t)ev[5]<<16);
        aw[q].u[3] = (uint32_t)ev[6] | ((uint32_t)ev[7]<<16);
        f32x4 m0 = *(const f32x4*)(m1v + 32*q + 8*g4);
        f32x4 m4 = *(const f32x4*)(m1v + 32*q + 8*g4 + 4);
        rp += bfu(ev[0])*m0[0] + bfu(ev[1])*m0[1] + bfu(ev[2])*m0[2] + bfu(ev[3])*m0[3]
            + bfu(ev[4])*m4[0] + bfu(ev[5])*m4[1] + bfu(ev[6])*m4[2] + bfu(ev[7])*m4[3];
      }
      rp += __shfl_xor(rp,16); rp += __shfl_xor(rp,32);
      rp *= inv_n;                       // R[mb+l15][128]
#pragma unroll
      for (int h = 0; h < 2; ++h) {      // col halves
        f32x4 racc[4];
#pragma unroll
        for (int i = 0; i < 4; ++i) racc[i] = (f32x4){0,0,0,0};
#pragma unroll
        for (int c4 = 0; c4 < 4; ++c4) {
          const int ct = 4*h + c4;
#pragma unroll
          for (int q = 0; q < 4; ++q) {
            short8 bm = *(const short8*)(GbB + (16*ct+l15)*BUFP + 32*q + 8*g4);
            racc[c4] = MFMA16(aw[q].s8, bm, racc[c4]);
          }
        }
        uint32_t ao[8];
        {
          uint4 q0 = h ? pf2 : pf0;
          uint4 q1 = h ? pf3 : pf1;
          ao[0]=q0.x; ao[1]=q0.y; ao[2]=q0.z; ao[3]=q0.w;
          ao[4]=q1.x; ao[5]=q1.y; ao[6]=q1.z; ao[7]=q1.w;
        }
        uint32_t an[8];
#pragma unroll
        for (int c4 = 0; c4 < 4; ++c4) {
          const int ct = 4*h + c4;
          uint16_t* zt = ZT + ztix(16*ct + l15, mb + 4*g4);
          uint2 hold = *(uint2*)zt;
          const float* gp = gml + (size_t)(mb + 4*g4)*129 + 16*ct + l15;
          float R0 = racc[c4][0]*inv_n, R1 = racc[c4][1]*inv_n;
          float R2 = racc[c4][2]*inv_n, R3 = racc[c4][3]*inv_n;
          float a0 = bflo(ao[2*c4]),   a1 = bfhi(ao[2*c4]);
          float a2 = bflo(ao[2*c4+1]), a3 = bfhi(ao[2*c4+1]);
          float z0 = bflo(hold.x) + bflo(lopk[ti][2*ct])   + R0 + a0;
          float z1 = bfhi(hold.x) + bfhi(lopk[ti][2*ct])   + R1 + a1;
          float z2 = bflo(hold.y) + bflo(lopk[ti][2*ct+1]) + R2 + a2;
          float z3 = bfhi(hold.y) + bfhi(lopk[ti][2*ct+1]) + R3 + a3;
          an[2*c4]   = pk2(a0 + R0*gp[0],   a1 + R1*gp[129]);
          an[2*c4+1] = pk2(a2 + R2*gp[258], a3 + R3*gp[387]);
          uint16_t h0 = f2bf(z0), h1 = f2bf(z1), h2 = f2bf(z2), h3 = f2bf(z3);
          *(uint2*)zt = make_uint2((uint32_t)h0 | ((uint32_t)h1<<16),
                                   (uint32_t)h2 | ((uint32_t)h3<<16));
          lopk[ti][2*ct]   = pk2(z0 - bfu(h0), z1 - bfu(h1));
          lopk[ti][2*ct+1] = pk2(z2 - bfu(h2), z3 - bfu(h3));
        }
        if (!last) {
          accb[((ti*4 + h*2 + 0) << 9) + tid] = make_uint4(an[0],an[1],an[2],an[3]);
          accb[((ti*4 + h*2 + 1) << 9) + tid] = make_uint4(an[4],an[5],an[6],an[7]);
        }
      }
      if (lane < 16) {                   // col-128 master update (f32 in LDS)
        const int m = mb + l15;
        float zb = zbar[m], a = acc128[m], ga = gml[m*129 + 128];
        float zn = zb + rp + a;
        zbar[m] = zn; acc128[m] = a + rp*ga;
      }
    }
    // r256[c] = sum_d Z[256][d]*Mc[c][d]  (4 lanes per c; z256f f32 broadcast)
    {
      const int c = tid >> 2, q = lane & 3;
      float s = 0;
#pragma unroll
      for (int j = 0; j < 8; ++j) {
        const int d0 = 32*q + 4*j;
        uint2 mv = *(const uint2*)(GbB + c*BUFP + d0);
        s += z256f[d0]*bflo(mv.x) + z256f[d0+1]*bfhi(mv.x)
           + z256f[d0+2]*bflo(mv.y) + z256f[d0+3]*bfhi(mv.y);
      }
      s += __shfl_xor(s,1); s += __shfl_xor(s,2);
      r256v = s;
    }
    if (w == 0) {                        // corner: R[256][128]
      const int d0 = lane*2;
      float s = z256f[d0]*m1v[d0] + z256f[d0+1]*m1v[d0+1];
      s += __shfl_xor(s,1); s += __shfl_xor(s,2); s += __shfl_xor(s,4);
      s += __shfl_xor(s,8); s += __shfl_xor(s,16); s += __shfl_xor(s,32);
      rcv = s;
    }
    __syncthreads();   // bar E: all z256f/GbB reads done

    // ===== D-256: update row 256 (f32 state only) =====
    if ((lane & 3) == 0) {
      const int c = tid >> 2;
      float R = r256v*inv_n;
      float z = z256f[c], a = acc256[c], ga = gml[256*129 + c];
      float zn = z + R + a;
      z256f[c] = zn; acc256[c] = a + R*ga;
    }
    if (w == 0 && lane == 0) {
      float R = rcv*inv_n;
      float ga = gml[256*129 + 128];
      float zn = zbar[256] + R + acc256[128];
      zbar[256] = zn; acc256[128] = acc256[128] + R*ga;
    }
  }

  // ---- coalesced f32 output from LDS (overwrites acc scratch region too) ----
  __syncthreads();
  for (int i2 = tid; i2 < 33153; i2 += 512) {
    int r = i2/129, c = i2 - r*129;
    float v;
    if (c < 128) v = (r == 256) ? z256f[c] : bfu(ZT[ztix(c, r)]);
    else         v = zbar[r];
    Zo[i2] = v;
  }
}

// allparam f32 -> bf16, both row-major: Pg[l][i][j]=P[i][j]; Qg[l][i][j]=Q[i][j].
__global__ void prep_params(const float* __restrict__ ap,
                            uint16_t* __restrict__ qg, uint16_t* __restrict__ pg)
{
  int t = blockIdx.x * 256 + threadIdx.x;   // 0..65535 = (l,i,j)
  int l = t >> 14, rem = t & 16383;
  pg[t] = f2bf(ap[(l*2 + 0)*16384 + rem]);
  qg[t] = f2bf(ap[(l*2 + 1)*16384 + rem]);
}

extern "C" void kernel_launch(void* const* d_in, const int* in_sizes, int n_in,
                              void* d_out, int out_size, void* d_ws, size_t ws_size,
                              hipStream_t stream)
{
  const float* Z  = (const float*)d_in[0];
  const float* ap = (const float*)d_in[1];
  const float* gm = (const float*)d_in[2];

  uint16_t* qg = (uint16_t*)d_ws;             // 4*128*128 bf16
  uint16_t* pg = qg + 4*128*128;              // 4*128*128 bf16 (256 KiB total)

  (void)hipFuncSetAttribute((const void*)tf_layers,
                            hipFuncAttributeMaxDynamicSharedMemorySize, LDS_TOTAL);

  prep_params<<<256, 256, 0, stream>>>(ap, qg, pg);
  tf_layers<<<512, 512, LDS_TOTAL, stream>>>(Z, gm, qg, pg, (float*)d_out);
}

// Round 11
// 256.901 us; speedup vs baseline: 1.5316x; 1.5316x over previous
//
#include <hip/hip_runtime.h>
#include <hip/hip_bf16.h>
#include <stdint.h>

// B=512, N=256, D=128, 4 layers. One block (512 thr, 8 waves) per batch.
// ALGORITHM (associativity): R = Attn*key/n = Z * (Qf * G * Pf^T) / n where
//   G = Z^T A Z = sum_{m<256} z_m z_m^T   (129x129 symmetric)
// Gbar = G[0:128,0:128], g = G[0:128,128]:
//   T1 = Gbar*P^T; M0 = Q*T1; m1 = Q*g;  R[:,c<128] = Zc*M0/n; R[:,128] = Zc*m1/n.
// STATE: master Z = bf16-hi in LDS (ZT, transposed [d][tok], pitch 280) +
// bf16-lo residual in regs (own rows). acc -> GLOBAL scratch (bf16-packed
// uint4, coalesced slot*512+tid) in the first 64 KB of this block's own d_out
// slice (layer 0 never reads it; output epilogue overwrites it).
// R11 = R9 (best, 268us) + exactly two safe deltas:
//  1) GbA/GbB ping-pong (Mc -> GbB): removes one barrier (4/layer). GbB's
//     previous readers finished before the prior layer's last barrier.
//  2) Scoped acc prefetch: the two uint4 acc loads issue at the top of each
//     h-iteration (+8 regs over ONE 16-MFMA window only). R10's version held
//     16 regs across the whole tile body and re-triggered spills (+300 MB).
// R10 lessons: ZT gather was never bank-conflicted (16 consecutive u16 = 8
// dwords/8 banks, broadcast); swizzle is useless here and its VALU+regs hurt.

using short8 = __attribute__((ext_vector_type(8))) short;
using f32x4  = __attribute__((ext_vector_type(4))) float;

#define MFMA16(A,B,C) __builtin_amdgcn_mfma_f32_16x16x32_bf16((A),(B),(C),0,0,0)

static __device__ __forceinline__ uint16_t f2bf(float f){
  union{__hip_bfloat16 h;uint16_t u;}c; c.h=__float2bfloat16(f); return c.u; }
static __device__ __forceinline__ uint32_t pk2(float lo,float hi){
  return (uint32_t)f2bf(lo) | ((uint32_t)f2bf(hi)<<16); }
static __device__ __forceinline__ float bfu(uint16_t u){ return __uint_as_float(((uint32_t)u)<<16); }
static __device__ __forceinline__ float bflo(uint32_t p){ return __uint_as_float(p<<16); }
static __device__ __forceinline__ float bfhi(uint32_t p){ return __uint_as_float(p&0xffff0000u); }

union F4 { uint32_t u[4]; short8 s8; };

// ---- LDS geometry ----
#define ZTP   280                           // ZT pitch (u16): [128][280], cols 0..256 used
#define BUFP  136                           // GbA/GbB pitch (u16)
#define SCRP  40                            // per-wave scratch pitch (u16)
#define ZT_OFF   0                          // 128*280*2 = 71,680
#define GBA_OFF  71680                      // 128*136*2 = 34,816
#define GBB_OFF  106496                     // 128*136*2 = 34,816
#define SCR_OFF  141312                     // 8*16*40*2 = 10,240
#define ZBAR_OFF 151552                     // 260*4 = 1,040
#define Z256_OFF 152592                     // 128*4 = 512
#define A128_OFF 153104                     // 256*4 = 1,024
#define A256_OFF 154128                     // 132*4 = 528
#define G_OFF    154656                     // 128*4 = 512
#define M1_OFF   155168                     // 128*4 = 512
#define LDS_TOTAL 155680

__global__ __launch_bounds__(512)
__attribute__((amdgpu_waves_per_eu(2, 2)))
void tf_layers(const float* __restrict__ Zin, const float* __restrict__ gamma,
               const uint16_t* __restrict__ Qg, const uint16_t* __restrict__ Pg,
               float* __restrict__ Zout)
{
  extern __shared__ char lds[];
  uint16_t* ZT    = (uint16_t*)(lds + ZT_OFF);   // [128][ZTP]: ZT[d][tok]=bf16 Z[tok][d]
  uint16_t* GbA   = (uint16_t*)(lds + GBA_OFF);  // [128][BUFP]: Gbar
  uint16_t* GbB   = (uint16_t*)(lds + GBB_OFF);  // [128][BUFP]: Mc[c][d]
  float*    zbar  = (float*)(lds + ZBAR_OFF);    // [257] f32 master col 128
  float*    z256f = (float*)(lds + Z256_OFF);    // [128] f32 master row 256
  float*    acc128= (float*)(lds + A128_OFF);    // [256] f32 acc col 128
  float*    acc256= (float*)(lds + A256_OFF);    // [129] f32 acc row 256
  float*    gv    = (float*)(lds + G_OFF);       // [128] g = Gbar[:,128]
  float*    m1v   = (float*)(lds + M1_OFF);      // [128] m1 = Q*g

  const int tid = threadIdx.x, lane = tid & 63, w = tid >> 6;
  const int l15 = lane & 15, g4 = lane >> 4;
  const int b = blockIdx.x;
  const float inv_n = 1.0f/256.0f;

  uint16_t* scr = (uint16_t*)(lds + SCR_OFF) + w * 16 * SCRP;

  const float* Zb = Zin + (size_t)b*33153;   // 257*129
  float*       Zo = Zout + (size_t)b*33153;

  // acc scratch: 16B-aligned, inside this block's own output slice (64 KB).
  uint4* accb = (uint4*)(((uintptr_t)Zo + 15) & ~(uintptr_t)15);

  // ---- init: ZT (transposed bf16 hi), zbar, z256f, acc arrays ----
  for (int i2 = tid; i2 < 33153; i2 += 512) {
    int r = i2/129, c = i2 - r*129;
    float v = Zb[i2];
    if (c < 128) { ZT[c*ZTP + r] = f2bf(v); if (r == 256) z256f[c] = v; }
    else zbar[r] = v;
  }
  if (tid < 256) acc128[tid] = 0.0f;
  if (tid < 129) acc256[tid] = 0.0f;

  // lo residual regs for own rows (D-frag layout: row mb+4g4+rr, col 16it+l15)
  uint32_t lopk[2][16];
#pragma unroll
  for (int ti = 0; ti < 2; ++ti) {
    const int mb = 16*w + 128*ti;
#pragma unroll
    for (int it = 0; it < 8; ++it) {
      const float* zp = Zb + (size_t)(mb + 4*g4)*129 + 16*it + l15;
      float v0 = zp[0], v1 = zp[129], v2 = zp[258], v3 = zp[387];
      lopk[ti][2*it]   = pk2(v0 - bfu(f2bf(v0)), v1 - bfu(f2bf(v1)));
      lopk[ti][2*it+1] = pk2(v2 - bfu(f2bf(v2)), v3 - bfu(f2bf(v3)));
    }
  }

#pragma unroll 1
  for (int l = 0; l < 4; ++l) {
    const uint16_t* Ql  = Qg + l*16384;
    const uint16_t* Pl  = Pg + l*16384;
    const float*    gml = gamma + l*33153;
    const bool last = (l == 3);

    __syncthreads();   // bar A: ZT/zbar/z256f stable

    // ===== G: Gbar[i][j] = sum_{m<256} Z[m][i]Z[m][j]; g[i] = sum Z[m][i]zbar[m]
    {
      f32x4 gacc[8];
#pragma unroll
      for (int jt = 0; jt < 8; ++jt) gacc[jt] = (f32x4){0,0,0,0};
#pragma unroll
      for (int mw = 0; mw < 8; ++mw) {
        short8 af = *(const short8*)(ZT + (16*w+l15)*ZTP + 32*mw + 8*g4);
#pragma unroll
        for (int jt = 0; jt < 8; ++jt) {
          short8 bf = *(const short8*)(ZT + (16*jt+l15)*ZTP + 32*mw + 8*g4);
          gacc[jt] = MFMA16(af, bf, gacc[jt]);
        }
      }
      // symmetric write: lane holds G[i=16w+4g4+rr][j=16jt+l15] -> GbA[j][i]
#pragma unroll
      for (int jt = 0; jt < 8; ++jt)
        *(uint2*)(GbA + (16*jt+l15)*BUFP + 16*w + 4*g4) =
            make_uint2(pk2(gacc[jt][0],gacc[jt][1]), pk2(gacc[jt][2],gacc[jt][3]));
      // g GEMV: i = tid>>2, 4 lanes x 64 tokens
      {
        const int i = tid >> 2, q = lane & 3;
        const uint16_t* zr = ZT + i*ZTP + 64*q;
        float s = 0;
#pragma unroll
        for (int j = 0; j < 16; ++j) {
          uint2 zv = *(const uint2*)(zr + 4*j);
          f32x4 z4 = *(const f32x4*)(zbar + 64*q + 4*j);
          s += bflo(zv.x)*z4[0] + bfhi(zv.x)*z4[1] + bflo(zv.y)*z4[2] + bfhi(zv.y)*z4[3];
        }
        s += __shfl_xor(s,1); s += __shfl_xor(s,2);
        if (q == 0) gv[i] = s;
      }
    }
    __syncthreads();   // bar B: Gbar, g ready

    // ===== T1 = Gbar*P^T -> regs (wave w: cols c=16w+l15); m1 = Q*g =====
    uint32_t t1t[16];
    {
      short8 bq[4];
#pragma unroll
      for (int k = 0; k < 4; ++k)
        bq[k] = *(const short8*)(Pl + (16*w+l15)*128 + 32*k + 8*g4);
#pragma unroll
      for (int it = 0; it < 8; ++it) {
        f32x4 d4 = {0,0,0,0};
#pragma unroll
        for (int k = 0; k < 4; ++k) {
          short8 ag = *(const short8*)(GbA + (16*it+l15)*BUFP + 32*k + 8*g4);
          d4 = MFMA16(ag, bq[k], d4);
        }
        t1t[2*it]   = pk2(d4[0], d4[1]);
        t1t[2*it+1] = pk2(d4[2], d4[3]);
      }
      // m1[d] = sum_e Q[d][e] g[e]
      {
        const int d = tid >> 2, q = lane & 3;
        float s = 0;
#pragma unroll
        for (int j = 0; j < 4; ++j) {
          short8 qv = *(const short8*)(Ql + d*128 + 32*q + 8*j);
          f32x4 g0 = *(const f32x4*)(gv + 32*q + 8*j);
          f32x4 g1 = *(const f32x4*)(gv + 32*q + 8*j + 4);
          s += bfu((uint16_t)qv[0])*g0[0] + bfu((uint16_t)qv[1])*g0[1]
             + bfu((uint16_t)qv[2])*g0[2] + bfu((uint16_t)qv[3])*g0[3]
             + bfu((uint16_t)qv[4])*g1[0] + bfu((uint16_t)qv[5])*g1[1]
             + bfu((uint16_t)qv[6])*g1[2] + bfu((uint16_t)qv[7])*g1[3];
        }
        s += __shfl_xor(s,1); s += __shfl_xor(s,2);
        if (q == 0) m1v[d] = s;
      }
    }
    // (no barrier: Mc writes GbB, whose last readers finished before bar A)

    // ===== Mc[c][d] = sum_e T1t[c][e] Q[d][e]  (wave w: rows c=16w+l15) =====
    {
      F4 bfr[4];
#pragma unroll
      for (int k2 = 0; k2 < 4; ++k2) {
        *(uint2*)(scr + l15*SCRP + 4*g4)      = make_uint2(t1t[4*k2],   t1t[4*k2+1]);
        *(uint2*)(scr + l15*SCRP + 16 + 4*g4) = make_uint2(t1t[4*k2+2], t1t[4*k2+3]);
        bfr[k2].s8 = *(const short8*)(scr + l15*SCRP + 8*g4);  // same-wave RAW
      }
#pragma unroll
      for (int dt = 0; dt < 8; ++dt) {
        f32x4 d4 = {0,0,0,0};
#pragma unroll
        for (int k2 = 0; k2 < 4; ++k2) {
          short8 aq = *(const short8*)(Ql + (16*dt+l15)*128 + 32*k2 + 8*g4);
          d4 = MFMA16(aq, bfr[k2].s8, d4);
        }
        *(uint2*)(GbB + (16*w+l15)*BUFP + 16*dt + 4*g4) =
            make_uint2(pk2(d4[0],d4[1]), pk2(d4[2],d4[3]));
      }
    }
    __syncthreads();   // bar D: Mc (GbB), m1 ready

    // ===== D-main: R = Z*Mc/n + fused update (own rows); r128; r256 =====
    float r256v = 0.0f, rcv = 0.0f;
#pragma unroll
    for (int ti = 0; ti < 2; ++ti) {
      const int mb = 16*w + 128*ti;
      F4 aw[4];
      float rp = 0;
#pragma unroll
      for (int q = 0; q < 4; ++q) {      // A-frags: Z own rows from ZT columns
        uint16_t ev[8];
#pragma unroll
        for (int j = 0; j < 8; ++j) ev[j] = ZT[(32*q + 8*g4 + j)*ZTP + mb + l15];
        aw[q].u[0] = (uint32_t)ev[0] | ((uint32_t)ev[1]<<16);
        aw[q].u[1] = (uint32_t)ev[2] | ((uint32_t)ev[3]<<16);
        aw[q].u[2] = (uint32_t)ev[4] | ((uint32_t)ev[5]<<16);
        aw[q].u[3] = (uint32_t)ev[6] | ((uint32_t)ev[7]<<16);
        f32x4 m0 = *(const f32x4*)(m1v + 32*q + 8*g4);
        f32x4 m4 = *(const f32x4*)(m1v + 32*q + 8*g4 + 4);
        rp += bfu(ev[0])*m0[0] + bfu(ev[1])*m0[1] + bfu(ev[2])*m0[2] + bfu(ev[3])*m0[3]
            + bfu(ev[4])*m4[0] + bfu(ev[5])*m4[1] + bfu(ev[6])*m4[2] + bfu(ev[7])*m4[3];
      }
      rp += __shfl_xor(rp,16); rp += __shfl_xor(rp,32);
      rp *= inv_n;                       // R[mb+l15][128]
#pragma unroll
      for (int h = 0; h < 2; ++h) {      // col halves
        // scoped acc prefetch: issues before the MFMA cluster, used after
        uint4 q0, q1;
        if (l > 0) {
          q0 = accb[(((ti*2 + h)*2 + 0) << 9) + tid];
          q1 = accb[(((ti*2 + h)*2 + 1) << 9) + tid];
        } else {
          q0 = make_uint4(0,0,0,0); q1 = make_uint4(0,0,0,0);
        }
        f32x4 racc[4];
#pragma unroll
        for (int i = 0; i < 4; ++i) racc[i] = (f32x4){0,0,0,0};
#pragma unroll
        for (int c4 = 0; c4 < 4; ++c4) {
          const int ct = 4*h + c4;
#pragma unroll
          for (int q = 0; q < 4; ++q) {
            short8 bm = *(const short8*)(GbB + (16*ct+l15)*BUFP + 32*q + 8*g4);
            racc[c4] = MFMA16(aw[q].s8, bm, racc[c4]);
          }
        }
        uint32_t ao[8];
        ao[0]=q0.x; ao[1]=q0.y; ao[2]=q0.z; ao[3]=q0.w;
        ao[4]=q1.x; ao[5]=q1.y; ao[6]=q1.z; ao[7]=q1.w;
        uint32_t an[8];
#pragma unroll
        for (int c4 = 0; c4 < 4; ++c4) {
          const int ct = 4*h + c4;
          uint16_t* zt = ZT + (16*ct+l15)*ZTP + mb + 4*g4;
          uint2 hold = *(uint2*)zt;
          const float* gp = gml + (size_t)(mb + 4*g4)*129 + 16*ct + l15;
          float R0 = racc[c4][0]*inv_n, R1 = racc[c4][1]*inv_n;
          float R2 = racc[c4][2]*inv_n, R3 = racc[c4][3]*inv_n;
          float a0 = bflo(ao[2*c4]),   a1 = bfhi(ao[2*c4]);
          float a2 = bflo(ao[2*c4+1]), a3 = bfhi(ao[2*c4+1]);
          float z0 = bflo(hold.x) + bflo(lopk[ti][2*ct])   + R0 + a0;
          float z1 = bfhi(hold.x) + bfhi(lopk[ti][2*ct])   + R1 + a1;
          float z2 = bflo(hold.y) + bflo(lopk[ti][2*ct+1]) + R2 + a2;
          float z3 = bfhi(hold.y) + bfhi(lopk[ti][2*ct+1]) + R3 + a3;
          an[2*c4]   = pk2(a0 + R0*gp[0],   a1 + R1*gp[129]);
          an[2*c4+1] = pk2(a2 + R2*gp[258], a3 + R3*gp[387]);
          uint16_t h0 = f2bf(z0), h1 = f2bf(z1), h2 = f2bf(z2), h3 = f2bf(z3);
          *(uint2*)zt = make_uint2((uint32_t)h0 | ((uint32_t)h1<<16),
                                   (uint32_t)h2 | ((uint32_t)h3<<16));
          lopk[ti][2*ct]   = pk2(z0 - bfu(h0), z1 - bfu(h1));
          lopk[ti][2*ct+1] = pk2(z2 - bfu(h2), z3 - bfu(h3));
        }
        if (!last) {
          accb[(((ti*2 + h)*2 + 0) << 9) + tid] = make_uint4(an[0],an[1],an[2],an[3]);
          accb[(((ti*2 + h)*2 + 1) << 9) + tid] = make_uint4(an[4],an[5],an[6],an[7]);
        }
      }
      if (lane < 16) {                   // col-128 master update (f32 in LDS)
        const int m = mb + l15;
        float zb = zbar[m], a = acc128[m], ga = gml[m*129 + 128];
        float zn = zb + rp + a;
        zbar[m] = zn; acc128[m] = a + rp*ga;
      }
    }
    // r256[c] = sum_d Z[256][d]*Mc[c][d]  (4 lanes per c)
    {
      const int c = tid >> 2, q = lane & 3;
      float s = 0;
#pragma unroll
      for (int j = 0; j < 8; ++j) {
        const int d0 = 32*q + 4*j;
        uint2 mv = *(const uint2*)(GbB + c*BUFP + d0);
        s += bfu(ZT[d0*ZTP + 256])*bflo(mv.x) + bfu(ZT[(d0+1)*ZTP + 256])*bfhi(mv.x)
           + bfu(ZT[(d0+2)*ZTP + 256])*bflo(mv.y) + bfu(ZT[(d0+3)*ZTP + 256])*bfhi(mv.y);
      }
      s += __shfl_xor(s,1); s += __shfl_xor(s,2);
      r256v = s;
    }
    if (w == 0) {                        // corner: R[256][128]
      const int d0 = lane*2;
      float s = bfu(ZT[d0*ZTP + 256])*m1v[d0] + bfu(ZT[(d0+1)*ZTP + 256])*m1v[d0+1];
      s += __shfl_xor(s,1); s += __shfl_xor(s,2); s += __shfl_xor(s,4);
      s += __shfl_xor(s,8); s += __shfl_xor(s,16); s += __shfl_xor(s,32);
      rcv = s;
    }
    __syncthreads();   // bar E: row-256 reads done

    // ===== D-256: update row 256 =====
    if ((lane & 3) == 0) {
      const int c = tid >> 2;
      float R = r256v*inv_n;
      float z = z256f[c], a = acc256[c], ga = gml[256*129 + c];
      float zn = z + R + a;
      z256f[c] = zn; acc256[c] = a + R*ga; ZT[c*ZTP + 256] = f2bf(zn);
    }
    if (w == 0 && lane == 0) {
      float R = rcv*inv_n;
      float ga = gml[256*129 + 128];
      float zn = zbar[256] + R + acc256[128];
      zbar[256] = zn; acc256[128] = acc256[128] + R*ga;
    }
  }

  // ---- coalesced f32 output from LDS (overwrites acc scratch region too) ----
  __syncthreads();
  for (int i2 = tid; i2 < 33153; i2 += 512) {
    int r = i2/129, c = i2 - r*129;
    float v;
    if (c < 128) v = (r == 256) ? z256f[c] : bfu(ZT[c*ZTP + r]);
    else         v = zbar[r];
    Zo[i2] = v;
  }
}

// allparam f32 -> bf16, both row-major: Pg[l][i][j]=P[i][j]; Qg[l][i][j]=Q[i][j].
__global__ void prep_params(const float* __restrict__ ap,
                            uint16_t* __restrict__ qg, uint16_t* __restrict__ pg)
{
  int t = blockIdx.x * 256 + threadIdx.x;   // 0..65535 = (l,i,j)
  int l = t >> 14, rem = t & 16383;
  pg[t] = f2bf(ap[(l*2 + 0)*16384 + rem]);
  qg[t] = f2bf(ap[(l*2 + 1)*16384 + rem]);
}

extern "C" void kernel_launch(void* const* d_in, const int* in_sizes, int n_in,
                              void* d_out, int out_size, void* d_ws, size_t ws_size,
                              hipStream_t stream)
{
  const float* Z  = (const float*)d_in[0];
  const float* ap = (const float*)d_in[1];
  const float* gm = (const float*)d_in[2];

  uint16_t* qg = (uint16_t*)d_ws;             // 4*128*128 bf16
  uint16_t* pg = qg + 4*128*128;              // 4*128*128 bf16 (256 KiB total)

  (void)hipFuncSetAttribute((const void*)tf_layers,
                            hipFuncAttributeMaxDynamicSharedMemorySize, LDS_TOTAL);

  prep_params<<<256, 256, 0, stream>>>(ap, qg, pg);
  tf_layers<<<512, 512, LDS_TOTAL, stream>>>(Z, gm, qg, pg, (float*)d_out);
}

// Round 13
// 253.970 us; speedup vs baseline: 1.5492x; 1.0115x over previous
//
#include <hip/hip_runtime.h>
#include <hip/hip_bf16.h>
#include <stdint.h>

// B=512, N=256, D=128, 4 layers. One block (512 thr, 8 waves) per batch.
// ALGORITHM (associativity): R = Attn*key/n = Z * (Qf * G * Pf^T) / n where
//   G = Z^T A Z = sum_{m<256} z_m z_m^T   (129x129 symmetric)
// Gbar = G[0:128,0:128], g = G[0:128,128]:
//   T1 = Gbar*P^T; M0 = Q*T1; m1 = Q*g;  R[:,c<128] = Zc*M0/n; R[:,128] = Zc*m1/n.
// STATE: master Z = bf16-hi in LDS (ZT, transposed [d][tok], pitch 264,
// tok<256 only; tok-256 row lives in f32 z256f) + bf16-lo residual in regs.
// acc -> GLOBAL scratch (bf16-packed uint4, coalesced slot*512+tid) in the
// first 64 KB of this block's own d_out slice (layer 0 never reads it;
// output epilogue overwrites it).
// R13 = R12 with the r256 GEMV bound fixed (jj<4, d<128 — R12's jj<8 read
// past the 152-u16 Gb row, corrupting R[256][*] -> absmax 7.86).
// R12's bank-conflict fixes retained (SQ_LDS_BANK_CONFLICT was 2.96e7 ~19%):
//  1) g/r256 GEMVs: q-interleaved at 8-elem granularity (uint4) ->
//     conflict-free (was 8-way/4-way with 64-elem chunks).
//  2) BUFP 136->152 (76 dw = 12 mod 32): Gb uint2 D-frag writes 4-way -> 2-way.
//  3) ZTP 280->264, ZT col-256 dropped (f32 z256f serves row 256).

using short8 = __attribute__((ext_vector_type(8))) short;
using f32x4  = __attribute__((ext_vector_type(4))) float;

#define MFMA16(A,B,C) __builtin_amdgcn_mfma_f32_16x16x32_bf16((A),(B),(C),0,0,0)

static __device__ __forceinline__ uint16_t f2bf(float f){
  union{__hip_bfloat16 h;uint16_t u;}c; c.h=__float2bfloat16(f); return c.u; }
static __device__ __forceinline__ uint32_t pk2(float lo,float hi){
  return (uint32_t)f2bf(lo) | ((uint32_t)f2bf(hi)<<16); }
static __device__ __forceinline__ float bfu(uint16_t u){ return __uint_as_float(((uint32_t)u)<<16); }
static __device__ __forceinline__ float bflo(uint32_t p){ return __uint_as_float(p<<16); }
static __device__ __forceinline__ float bfhi(uint32_t p){ return __uint_as_float(p&0xffff0000u); }

union F4 { uint32_t u[4]; short8 s8; };

// ---- LDS geometry ----
#define ZTP   264                           // ZT pitch (u16): [128][264], tok 0..255
#define BUFP  152                           // GbA/GbB pitch (u16): 76 dw = 12 mod 32
#define SCRP  40                            // per-wave scratch pitch (u16)
#define ZT_OFF   0                          // 128*264*2 = 67,584
#define GBA_OFF  67584                      // 128*152*2 = 38,912
#define GBB_OFF  106496                     // 128*152*2 = 38,912
#define SCR_OFF  145408                     // 8*16*40*2 = 10,240
#define ZBAR_OFF 155648                     // 260*4 = 1,040
#define Z256_OFF 156688                     // 128*4 = 512
#define A128_OFF 157200                     // 256*4 = 1,024
#define A256_OFF 158224                     // 132*4 = 528
#define G_OFF    158752                     // 128*4 = 512
#define M1_OFF   159264                     // 128*4 = 512
#define LDS_TOTAL 159776

__global__ __launch_bounds__(512)
__attribute__((amdgpu_waves_per_eu(2, 2)))
void tf_layers(const float* __restrict__ Zin, const float* __restrict__ gamma,
               const uint16_t* __restrict__ Qg, const uint16_t* __restrict__ Pg,
               float* __restrict__ Zout)
{
  extern __shared__ char lds[];
  uint16_t* ZT    = (uint16_t*)(lds + ZT_OFF);   // [128][ZTP]: ZT[d][tok]=bf16 Z[tok][d]
  uint16_t* GbA   = (uint16_t*)(lds + GBA_OFF);  // [128][BUFP]: Gbar
  uint16_t* GbB   = (uint16_t*)(lds + GBB_OFF);  // [128][BUFP]: Mc[c][d]
  float*    zbar  = (float*)(lds + ZBAR_OFF);    // [257] f32 master col 128
  float*    z256f = (float*)(lds + Z256_OFF);    // [128] f32 master row 256
  float*    acc128= (float*)(lds + A128_OFF);    // [256] f32 acc col 128
  float*    acc256= (float*)(lds + A256_OFF);    // [129] f32 acc row 256
  float*    gv    = (float*)(lds + G_OFF);       // [128] g = Gbar[:,128]
  float*    m1v   = (float*)(lds + M1_OFF);      // [128] m1 = Q*g

  const int tid = threadIdx.x, lane = tid & 63, w = tid >> 6;
  const int l15 = lane & 15, g4 = lane >> 4;
  const int b = blockIdx.x;
  const float inv_n = 1.0f/256.0f;

  uint16_t* scr = (uint16_t*)(lds + SCR_OFF) + w * 16 * SCRP;

  const float* Zb = Zin + (size_t)b*33153;   // 257*129
  float*       Zo = Zout + (size_t)b*33153;

  // acc scratch: 16B-aligned, inside this block's own output slice (64 KB).
  uint4* accb = (uint4*)(((uintptr_t)Zo + 15) & ~(uintptr_t)15);

  // ---- init: ZT (transposed bf16 hi, tok<256), zbar, z256f, acc arrays ----
  for (int i2 = tid; i2 < 33153; i2 += 512) {
    int r = i2/129, c = i2 - r*129;
    float v = Zb[i2];
    if (c < 128) { if (r < 256) ZT[c*ZTP + r] = f2bf(v); else z256f[c] = v; }
    else zbar[r] = v;
  }
  if (tid < 256) acc128[tid] = 0.0f;
  if (tid < 129) acc256[tid] = 0.0f;

  // lo residual regs for own rows (D-frag layout: row mb+4g4+rr, col 16it+l15)
  uint32_t lopk[2][16];
#pragma unroll
  for (int ti = 0; ti < 2; ++ti) {
    const int mb = 16*w + 128*ti;
#pragma unroll
    for (int it = 0; it < 8; ++it) {
      const float* zp = Zb + (size_t)(mb + 4*g4)*129 + 16*it + l15;
      float v0 = zp[0], v1 = zp[129], v2 = zp[258], v3 = zp[387];
      lopk[ti][2*it]   = pk2(v0 - bfu(f2bf(v0)), v1 - bfu(f2bf(v1)));
      lopk[ti][2*it+1] = pk2(v2 - bfu(f2bf(v2)), v3 - bfu(f2bf(v3)));
    }
  }

#pragma unroll 1
  for (int l = 0; l < 4; ++l) {
    const uint16_t* Ql  = Qg + l*16384;
    const uint16_t* Pl  = Pg + l*16384;
    const float*    gml = gamma + l*33153;
    const bool last = (l == 3);

    __syncthreads();   // bar A: ZT/zbar/z256f stable

    // ===== G: Gbar[i][j] = sum_{m<256} Z[m][i]Z[m][j]; g[i] = sum Z[m][i]zbar[m]
    {
      f32x4 gacc[8];
#pragma unroll
      for (int jt = 0; jt < 8; ++jt) gacc[jt] = (f32x4){0,0,0,0};
#pragma unroll
      for (int mw = 0; mw < 8; ++mw) {
        short8 af = *(const short8*)(ZT + (16*w+l15)*ZTP + 32*mw + 8*g4);
#pragma unroll
        for (int jt = 0; jt < 8; ++jt) {
          short8 bf = *(const short8*)(ZT + (16*jt+l15)*ZTP + 32*mw + 8*g4);
          gacc[jt] = MFMA16(af, bf, gacc[jt]);
        }
      }
      // symmetric write: lane holds G[i=16w+4g4+rr][j=16jt+l15] -> GbA[j][i]
#pragma unroll
      for (int jt = 0; jt < 8; ++jt)
        *(uint2*)(GbA + (16*jt+l15)*BUFP + 16*w + 4*g4) =
            make_uint2(pk2(gacc[jt][0],gacc[jt][1]), pk2(gacc[jt][2],gacc[jt][3]));
      // g GEMV: i = tid>>2; q-interleaved 8-tok blocks (conflict-free), 256 toks
      {
        const int i = tid >> 2, q = lane & 3;
        float s = 0;
#pragma unroll
        for (int jj = 0; jj < 8; ++jj) {
          const int t0 = 8*q + 32*jj;
          uint4 zv = *(const uint4*)(ZT + i*ZTP + t0);
          f32x4 z0 = *(const f32x4*)(zbar + t0);
          f32x4 z1 = *(const f32x4*)(zbar + t0 + 4);
          s += bflo(zv.x)*z0[0] + bfhi(zv.x)*z0[1] + bflo(zv.y)*z0[2] + bfhi(zv.y)*z0[3]
             + bflo(zv.z)*z1[0] + bfhi(zv.z)*z1[1] + bflo(zv.w)*z1[2] + bfhi(zv.w)*z1[3];
        }
        s += __shfl_xor(s,1); s += __shfl_xor(s,2);
        if (q == 0) gv[i] = s;
      }
    }
    __syncthreads();   // bar B: Gbar, g ready

    // ===== T1 = Gbar*P^T -> regs (wave w: cols c=16w+l15); m1 = Q*g =====
    uint32_t t1t[16];
    {
      short8 bq[4];
#pragma unroll
      for (int k = 0; k < 4; ++k)
        bq[k] = *(const short8*)(Pl + (16*w+l15)*128 + 32*k + 8*g4);
#pragma unroll
      for (int it = 0; it < 8; ++it) {
        f32x4 d4 = {0,0,0,0};
#pragma unroll
        for (int k = 0; k < 4; ++k) {
          short8 ag = *(const short8*)(GbA + (16*it+l15)*BUFP + 32*k + 8*g4);
          d4 = MFMA16(ag, bq[k], d4);
        }
        t1t[2*it]   = pk2(d4[0], d4[1]);
        t1t[2*it+1] = pk2(d4[2], d4[3]);
      }
      // m1[d] = sum_e Q[d][e] g[e]  (gv reads are broadcast: free)
      {
        const int d = tid >> 2, q = lane & 3;
        float s = 0;
#pragma unroll
        for (int j = 0; j < 4; ++j) {
          short8 qv = *(const short8*)(Ql + d*128 + 32*q + 8*j);
          f32x4 g0 = *(const f32x4*)(gv + 32*q + 8*j);
          f32x4 g1 = *(const f32x4*)(gv + 32*q + 8*j + 4);
          s += bfu((uint16_t)qv[0])*g0[0] + bfu((uint16_t)qv[1])*g0[1]
             + bfu((uint16_t)qv[2])*g0[2] + bfu((uint16_t)qv[3])*g0[3]
             + bfu((uint16_t)qv[4])*g1[0] + bfu((uint16_t)qv[5])*g1[1]
             + bfu((uint16_t)qv[6])*g1[2] + bfu((uint16_t)qv[7])*g1[3];
        }
        s += __shfl_xor(s,1); s += __shfl_xor(s,2);
        if (q == 0) m1v[d] = s;
      }
    }
    // (no barrier: Mc writes GbB, whose last readers finished before bar A)

    // ===== Mc[c][d] = sum_e T1t[c][e] Q[d][e]  (wave w: rows c=16w+l15) =====
    {
      F4 bfr[4];
#pragma unroll
      for (int k2 = 0; k2 < 4; ++k2) {
        *(uint2*)(scr + l15*SCRP + 4*g4)      = make_uint2(t1t[4*k2],   t1t[4*k2+1]);
        *(uint2*)(scr + l15*SCRP + 16 + 4*g4) = make_uint2(t1t[4*k2+2], t1t[4*k2+3]);
        bfr[k2].s8 = *(const short8*)(scr + l15*SCRP + 8*g4);  // same-wave RAW
      }
#pragma unroll
      for (int dt = 0; dt < 8; ++dt) {
        f32x4 d4 = {0,0,0,0};
#pragma unroll
        for (int k2 = 0; k2 < 4; ++k2) {
          short8 aq = *(const short8*)(Ql + (16*dt+l15)*128 + 32*k2 + 8*g4);
          d4 = MFMA16(aq, bfr[k2].s8, d4);
        }
        *(uint2*)(GbB + (16*w+l15)*BUFP + 16*dt + 4*g4) =
            make_uint2(pk2(d4[0],d4[1]), pk2(d4[2],d4[3]));
      }
    }
    __syncthreads();   // bar D: Mc (GbB), m1 ready

    // ===== D-main: R = Z*Mc/n + fused update (own rows); r128; r256 =====
    float r256v = 0.0f, rcv = 0.0f;
#pragma unroll
    for (int ti = 0; ti < 2; ++ti) {
      const int mb = 16*w + 128*ti;
      F4 aw[4];
      float rp = 0;
#pragma unroll
      for (int q = 0; q < 4; ++q) {      // A-frags: Z own rows from ZT columns
        uint16_t ev[8];
#pragma unroll
        for (int j = 0; j < 8; ++j) ev[j] = ZT[(32*q + 8*g4 + j)*ZTP + mb + l15];
        aw[q].u[0] = (uint32_t)ev[0] | ((uint32_t)ev[1]<<16);
        aw[q].u[1] = (uint32_t)ev[2] | ((uint32_t)ev[3]<<16);
        aw[q].u[2] = (uint32_t)ev[4] | ((uint32_t)ev[5]<<16);
        aw[q].u[3] = (uint32_t)ev[6] | ((uint32_t)ev[7]<<16);
        f32x4 m0 = *(const f32x4*)(m1v + 32*q + 8*g4);
        f32x4 m4 = *(const f32x4*)(m1v + 32*q + 8*g4 + 4);
        rp += bfu(ev[0])*m0[0] + bfu(ev[1])*m0[1] + bfu(ev[2])*m0[2] + bfu(ev[3])*m0[3]
            + bfu(ev[4])*m4[0] + bfu(ev[5])*m4[1] + bfu(ev[6])*m4[2] + bfu(ev[7])*m4[3];
      }
      rp += __shfl_xor(rp,16); rp += __shfl_xor(rp,32);
      rp *= inv_n;                       // R[mb+l15][128]
#pragma unroll
      for (int h = 0; h < 2; ++h) {      // col halves
        // scoped acc prefetch: issues before the MFMA cluster, used after
        uint4 q0, q1;
        if (l > 0) {
          q0 = accb[(((ti*2 + h)*2 + 0) << 9) + tid];
          q1 = accb[(((ti*2 + h)*2 + 1) << 9) + tid];
        } else {
          q0 = make_uint4(0,0,0,0); q1 = make_uint4(0,0,0,0);
        }
        f32x4 racc[4];
#pragma unroll
        for (int i = 0; i < 4; ++i) racc[i] = (f32x4){0,0,0,0};
#pragma unroll
        for (int c4 = 0; c4 < 4; ++c4) {
          const int ct = 4*h + c4;
#pragma unroll
          for (int q = 0; q < 4; ++q) {
            short8 bm = *(const short8*)(GbB + (16*ct+l15)*BUFP + 32*q + 8*g4);
            racc[c4] = MFMA16(aw[q].s8, bm, racc[c4]);
          }
        }
        uint32_t ao[8];
        ao[0]=q0.x; ao[1]=q0.y; ao[2]=q0.z; ao[3]=q0.w;
        ao[4]=q1.x; ao[5]=q1.y; ao[6]=q1.z; ao[7]=q1.w;
        uint32_t an[8];
#pragma unroll
        for (int c4 = 0; c4 < 4; ++c4) {
          const int ct = 4*h + c4;
          uint16_t* zt = ZT + (16*ct+l15)*ZTP + mb + 4*g4;
          uint2 hold = *(uint2*)zt;
          const float* gp = gml + (size_t)(mb + 4*g4)*129 + 16*ct + l15;
          float R0 = racc[c4][0]*inv_n, R1 = racc[c4][1]*inv_n;
          float R2 = racc[c4][2]*inv_n, R3 = racc[c4][3]*inv_n;
          float a0 = bflo(ao[2*c4]),   a1 = bfhi(ao[2*c4]);
          float a2 = bflo(ao[2*c4+1]), a3 = bfhi(ao[2*c4+1]);
          float z0 = bflo(hold.x) + bflo(lopk[ti][2*ct])   + R0 + a0;
          float z1 = bfhi(hold.x) + bfhi(lopk[ti][2*ct])   + R1 + a1;
          float z2 = bflo(hold.y) + bflo(lopk[ti][2*ct+1]) + R2 + a2;
          float z3 = bfhi(hold.y) + bfhi(lopk[ti][2*ct+1]) + R3 + a3;
          an[2*c4]   = pk2(a0 + R0*gp[0],   a1 + R1*gp[129]);
          an[2*c4+1] = pk2(a2 + R2*gp[258], a3 + R3*gp[387]);
          uint16_t h0 = f2bf(z0), h1 = f2bf(z1), h2 = f2bf(z2), h3 = f2bf(z3);
          *(uint2*)zt = make_uint2((uint32_t)h0 | ((uint32_t)h1<<16),
                                   (uint32_t)h2 | ((uint32_t)h3<<16));
          lopk[ti][2*ct]   = pk2(z0 - bfu(h0), z1 - bfu(h1));
          lopk[ti][2*ct+1] = pk2(z2 - bfu(h2), z3 - bfu(h3));
        }
        if (!last) {
          accb[(((ti*2 + h)*2 + 0) << 9) + tid] = make_uint4(an[0],an[1],an[2],an[3]);
          accb[(((ti*2 + h)*2 + 1) << 9) + tid] = make_uint4(an[4],an[5],an[6],an[7]);
        }
      }
      if (lane < 16) {                   // col-128 master update (f32 in LDS)
        const int m = mb + l15;
        float zb = zbar[m], a = acc128[m], ga = gml[m*129 + 128];
        float zn = zb + rp + a;
        zbar[m] = zn; acc128[m] = a + rp*ga;
      }
    }
    // r256[c] = sum_{d<128} Z[256][d]*Mc[c][d] — q-interleaved 8-d blocks
    {
      const int c = tid >> 2, q = lane & 3;
      float s = 0;
#pragma unroll
      for (int jj = 0; jj < 4; ++jj) {   // 4 lanes x 4 x 8 = 128 d's
        const int d0 = 8*q + 32*jj;
        uint4 mv = *(const uint4*)(GbB + c*BUFP + d0);
        f32x4 z0 = *(const f32x4*)(z256f + d0);
        f32x4 z1 = *(const f32x4*)(z256f + d0 + 4);
        s += z0[0]*bflo(mv.x) + z0[1]*bfhi(mv.x) + z0[2]*bflo(mv.y) + z0[3]*bfhi(mv.y)
           + z1[0]*bflo(mv.z) + z1[1]*bfhi(mv.z) + z1[2]*bflo(mv.w) + z1[3]*bfhi(mv.w);
      }
      s += __shfl_xor(s,1); s += __shfl_xor(s,2);
      r256v = s;
    }
    if (w == 0) {                        // corner: R[256][128]
      const int d0 = lane*2;
      float s = z256f[d0]*m1v[d0] + z256f[d0+1]*m1v[d0+1];
      s += __shfl_xor(s,1); s += __shfl_xor(s,2); s += __shfl_xor(s,4);
      s += __shfl_xor(s,8); s += __shfl_xor(s,16); s += __shfl_xor(s,32);
      rcv = s;
    }
    __syncthreads();   // bar E: all z256f/GbB reads done

    // ===== D-256: update row 256 (f32 state only) =====
    if ((lane & 3) == 0) {
      const int c = tid >> 2;
      float R = r256v*inv_n;
      float z = z256f[c], a = acc256[c], ga = gml[256*129 + c];
      float zn = z + R + a;
      z256f[c] = zn; acc256[c] = a + R*ga;
    }
    if (w == 0 && lane == 0) {
      float R = rcv*inv_n;
      float ga = gml[256*129 + 128];
      float zn = zbar[256] + R + acc256[128];
      zbar[256] = zn; acc256[128] = acc256[128] + R*ga;
    }
  }

  // ---- coalesced f32 output from LDS (overwrites acc scratch region too) ----
  __syncthreads();
  for (int i2 = tid; i2 < 33153; i2 += 512) {
    int r = i2/129, c = i2 - r*129;
    float v;
    if (c < 128) v = (r == 256) ? z256f[c] : bfu(ZT[c*ZTP + r]);
    else         v = zbar[r];
    Zo[i2] = v;
  }
}

// allparam f32 -> bf16, both row-major: Pg[l][i][j]=P[i][j]; Qg[l][i][j]=Q[i][j].
__global__ void prep_params(const float* __restrict__ ap,
                            uint16_t* __restrict__ qg, uint16_t* __restrict__ pg)
{
  int t = blockIdx.x * 256 + threadIdx.x;   // 0..65535 = (l,i,j)
  int l = t >> 14, rem = t & 16383;
  pg[t] = f2bf(ap[(l*2 + 0)*16384 + rem]);
  qg[t] = f2bf(ap[(l*2 + 1)*16384 + rem]);
}

extern "C" void kernel_launch(void* const* d_in, const int* in_sizes, int n_in,
                              void* d_out, int out_size, void* d_ws, size_t ws_size,
                              hipStream_t stream)
{
  const float* Z  = (const float*)d_in[0];
  const float* ap = (const float*)d_in[1];
  const float* gm = (const float*)d_in[2];

  uint16_t* qg = (uint16_t*)d_ws;             // 4*128*128 bf16
  uint16_t* pg = qg + 4*128*128;              // 4*128*128 bf16 (256 KiB total)

  (void)hipFuncSetAttribute((const void*)tf_layers,
                            hipFuncAttributeMaxDynamicSharedMemorySize, LDS_TOTAL);

  prep_params<<<256, 256, 0, stream>>>(ap, qg, pg);
  tf_layers<<<512, 512, LDS_TOTAL, stream>>>(Z, gm, qg, pg, (float*)d_out);
}